// Round 7
// baseline (290.510 us; speedup 1.0000x reference)
//
#include <hip/hip_runtime.h>
#include <hip/hip_bf16.h>
#include <cstdint>
#include <cstddef>

#define D 128           // feature dim
#define KNB 10          // NUM_NEIGHBORS
#define CAPS 64         // per-node scatter capacity (bench max degree ~48; P(deg>=64)~1e-19)

typedef __attribute__((ext_vector_type(8))) short short8;   // MFMA A/B frag (8 bf16)
typedef __attribute__((ext_vector_type(4))) float floatx4;  // MFMA C/D frag

__device__ inline unsigned bf16_rne(float f) {
  unsigned u = __builtin_bit_cast(unsigned, f);
  return (u + 0x7FFFu + ((u >> 16) & 1u)) >> 16;
}
__device__ inline float bflo(unsigned u) { return __builtin_bit_cast(float, u << 16); }
__device__ inline float bfhi(unsigned u) { return __builtin_bit_cast(float, u & 0xFFFF0000u); }

// ---------------------------------------------------------------------------
// k_xcast_zero: blocks [0,zblocks) zero the per-node cursors; the rest
// stream-cast x fp32 -> xh bf16 pairs (independent work, one launch).
// ---------------------------------------------------------------------------
__global__ __launch_bounds__(256) void k_xcast_zero(const float* __restrict__ x,
                                                    unsigned* __restrict__ xh, int n8,
                                                    int* __restrict__ cur, int N,
                                                    int zblocks) {
  if ((int)blockIdx.x < zblocks) {
    int i = blockIdx.x * 256 + threadIdx.x;
    if (i < N) cur[i] = 0;
    return;
  }
  int t = ((int)blockIdx.x - zblocks) * 256 + threadIdx.x;
  if (t >= n8) return;
  const float4* p = reinterpret_cast<const float4*>(x) + (size_t)t * 2;
  float4 a = p[0], b = p[1];
  uint4 o;
  o.x = bf16_rne(a.x) | (bf16_rne(a.y) << 16);
  o.y = bf16_rne(a.z) | (bf16_rne(a.w) << 16);
  o.z = bf16_rne(b.x) | (bf16_rne(b.y) << 16);
  o.w = bf16_rne(b.z) | (bf16_rne(b.w) << 16);
  reinterpret_cast<uint4*>(xh)[t] = o;
}

// ---------------------------------------------------------------------------
// k_scatter: direct per-node counting scatter. ONE global atomicAdd per edge
// (L2-resident cur[N]); entry {eid, col} lands at binned[r*caps + k].
// R12 FIX (R6 post-mortem): R11's plane-major binned[k*N + r] made every 8B
// write dirty its own 64B line -> WRITE_SIZE 104 MB (= 1.6M x 64B exactly),
// 129 us at 0.87 TB/s. R-MAJOR clusters a node's entries in one 512B region:
// ~2-3 touched lines/node (~17 MB) instead of 16 (~104 MB).
// HARDENING: r range-checked; k capped at caps; col read coalesced here so
// select/fused never touch ei randomly.
// ---------------------------------------------------------------------------
__global__ __launch_bounds__(256) void k_scatter(const int* __restrict__ row,
                                                 const int* __restrict__ col,
                                                 int E, int N, int caps,
                                                 int* __restrict__ cur,
                                                 uint2* __restrict__ binned) {
  int e = blockIdx.x * 256 + threadIdx.x;
  if (e >= E) return;
  int r = row[e];
  unsigned c = (unsigned)col[e];
  if ((unsigned)r < (unsigned)N) {
    int k = atomicAdd(&cur[r], 1);
    if (k < caps) binned[(size_t)r * caps + k] = make_uint2((unsigned)e, c);
  }
}

// ---------------------------------------------------------------------------
// k_select_flat: one THREAD per node. Scans the node's <=cnt entries
// (sequential within its 512B region — each 64B line serves 8 k-iterations,
// L2/L3-resident since just written), keeps the 10 smallest eids via a
// branchless 10-register compare-swap chain — zero atomics, zero LDS,
// all-static register indexing (rule #20). The selected SET is deterministic
// (10 smallest eids) regardless of the nondeterministic scatter order =>
// bit-identical downstream arithmetic.
// HARDENING: cnt clamped to [0,caps]; slot valid iff e10[k] < E (rejects
// the 0xFFFFFFFF init and any poison); consumer re-checks col < N.
// ---------------------------------------------------------------------------
__global__ __launch_bounds__(256) void k_select_flat(const uint2* __restrict__ binned,
                                                     const int* __restrict__ cur,
                                                     int* __restrict__ slots_g,
                                                     int N, int E, int caps) {
  int r = blockIdx.x * 256 + threadIdx.x;
  if (r >= N) return;
  int cnt = cur[r];
  cnt = min(max(cnt, 0), caps);

  unsigned e10[KNB], c10[KNB];
#pragma unroll
  for (int k = 0; k < KNB; ++k) { e10[k] = 0xFFFFFFFFu; c10[k] = 0xFFFFFFFFu; }

  for (int k = 0; k < cnt; ++k) {
    uint2 en = binned[(size_t)r * caps + k];
    unsigned ev = en.x, cv = en.y;
#pragma unroll
    for (int j = 0; j < KNB; ++j) {
      bool lt = ev < e10[j];
      unsigned te = lt ? e10[j] : ev;
      unsigned tc = lt ? c10[j] : cv;
      e10[j] = lt ? ev : e10[j];
      c10[j] = lt ? cv : c10[j];
      ev = te; cv = tc;
    }
  }

#pragma unroll
  for (int k = 0; k < KNB; ++k)
    slots_g[(size_t)r * KNB + k] = (e10[k] < (unsigned)E) ? (int)c10[k] : -1;
}

// ---------------------------------------------------------------------------
// k_fused: aggregation + GEMM in ONE kernel (R8-verified: 62 µs = traffic
// floor 214 MB at the ~3.5 TB/s random-granule ceiling; occupancy-
// insensitive — UNCHANGED).
// Per 128-node block (256 thr, 69.6 KB LDS):
//  phase W: stage W fp32->bf16 into sW (issued first, long-latency).
//  phase G: 16 16-lane groups x 8 nodes: 10 col-broadcasts + 10 independent
//           uint4 bf16 gathers, fp32 mean, pack -> sA A-tile.
//  phase M: verified 16x16x32 bf16 MFMA body, bias add, fp32 out.
// HARDENING (load-bearing): col range-checked ((unsigned)c < N) before
// indexing xh; invalid/SENT/poison -> weight 0, gather row 0 (hot line).
// ---------------------------------------------------------------------------
#define GBN 128
#define LDK 136

__global__ __launch_bounds__(256) void k_fused(const unsigned* __restrict__ xh,
                                               const float* __restrict__ x,
                                               const int* __restrict__ slots,
                                               const float* __restrict__ Wm,
                                               const float* __restrict__ bias,
                                               float* __restrict__ out, int N) {
  __shared__ unsigned short sA[GBN * LDK];
  __shared__ unsigned short sW[GBN * LDK];
  const int tid = threadIdx.x;
  const int n0 = blockIdx.x * GBN;

  // ---- phase W: W fp32 -> bf16 into sW ----
#pragma unroll
  for (int i = 0; i < 16; ++i) {
    int q = i * 256 + tid;
    int row = q >> 5;
    int c4 = q & 31;
    float4 wv = reinterpret_cast<const float4*>(Wm + (size_t)row * D)[c4];
    ushort4 uw;
    uw.x = (unsigned short)bf16_rne(wv.x);
    uw.y = (unsigned short)bf16_rne(wv.y);
    uw.z = (unsigned short)bf16_rne(wv.z);
    uw.w = (unsigned short)bf16_rne(wv.w);
    *reinterpret_cast<ushort4*>(&sW[row * LDK + c4 * 4]) = uw;
  }

  // ---- phase G: aggregate 8 nodes per 16-lane group, write A-tile ----
  const int lane = tid & 63;
  const int j16 = lane & 15;       // dim-octet index within the 256B row
  const int gsh = lane & 48;       // group base lane within wave
  const int grp = tid >> 4;        // 0..15

  const uint4* xh4 = reinterpret_cast<const uint4*>(xh);

  for (int nn = 0; nn < 8; ++nn) {
    const int row = nn * 16 + grp;         // 0..127
    const int n = n0 + row;
    const bool active = n < N;

    int scol = -1;
    if (active && j16 < KNB) scol = slots[(size_t)n * KNB + j16];
    bool valid = (unsigned)scol < (unsigned)N;
    unsigned long long bal = __ballot(valid);
    int nsel = __popc((unsigned)((bal >> gsh) & 0xFFFFull));

    // broadcast the group's 10 cols, then 10 independent 16B gathers
    int ck[KNB];
#pragma unroll
    for (int k = 0; k < KNB; ++k) ck[k] = __shfl(scol, gsh + k);

    uint4 uu[KNB];
    float wj[KNB];
#pragma unroll
    for (int k = 0; k < KNB; ++k) {
      bool vk = (unsigned)ck[k] < (unsigned)N;
      wj[k] = vk ? 1.f : 0.f;
      uu[k] = xh4[(size_t)(vk ? ck[k] : 0) * 16 + j16];
    }

    float acc[8];
#pragma unroll
    for (int q = 0; q < 8; ++q) acc[q] = 0.f;

    if (active) {
      if (nsel > 0) {
#pragma unroll
        for (int k = 0; k < KNB; ++k) {
          float w = wj[k];
          acc[0] += w * bflo(uu[k].x); acc[1] += w * bfhi(uu[k].x);
          acc[2] += w * bflo(uu[k].y); acc[3] += w * bfhi(uu[k].y);
          acc[4] += w * bflo(uu[k].z); acc[5] += w * bfhi(uu[k].z);
          acc[6] += w * bflo(uu[k].w); acc[7] += w * bfhi(uu[k].w);
        }
        float sc = 1.f / (float)nsel;
#pragma unroll
        for (int q = 0; q < 8; ++q) acc[q] *= sc;
      } else {
        const float4* xr = reinterpret_cast<const float4*>(x + (size_t)n * D);
        float4 v0 = xr[j16 * 2], v1 = xr[j16 * 2 + 1];
        acc[0] = v0.x; acc[1] = v0.y; acc[2] = v0.z; acc[3] = v0.w;
        acc[4] = v1.x; acc[5] = v1.y; acc[6] = v1.z; acc[7] = v1.w;
      }
    }

    ushort4 ow;
    ow.x = (unsigned short)bf16_rne(acc[0]);
    ow.y = (unsigned short)bf16_rne(acc[1]);
    ow.z = (unsigned short)bf16_rne(acc[2]);
    ow.w = (unsigned short)bf16_rne(acc[3]);
    ushort4 ow2;
    ow2.x = (unsigned short)bf16_rne(acc[4]);
    ow2.y = (unsigned short)bf16_rne(acc[5]);
    ow2.z = (unsigned short)bf16_rne(acc[6]);
    ow2.w = (unsigned short)bf16_rne(acc[7]);
    *reinterpret_cast<ushort4*>(&sA[row * LDK + j16 * 8]) = ow;
    *reinterpret_cast<ushort4*>(&sA[row * LDK + j16 * 8 + 4]) = ow2;
  }
  __syncthreads();

  // ---- phase M: verified MFMA body (frag layouts HW-verified m89) ----
  const int wave = tid >> 6;
  const int lrow = lane & 15;
  const int quad = lane >> 4;

  floatx4 acc[2][8];
#pragma unroll
  for (int mt = 0; mt < 2; ++mt)
#pragma unroll
    for (int nt = 0; nt < 8; ++nt)
      acc[mt][nt] = (floatx4){0.f, 0.f, 0.f, 0.f};

  float bv[8];
#pragma unroll
  for (int nt = 0; nt < 8; ++nt) bv[nt] = bias[nt * 16 + lrow];

#pragma unroll
  for (int ks = 0; ks < 4; ++ks) {
    int koff = ks * 32 + quad * 8;
    short8 a0 = *reinterpret_cast<const short8*>(&sA[(wave * 32 + lrow) * LDK + koff]);
    short8 a1 = *reinterpret_cast<const short8*>(&sA[(wave * 32 + 16 + lrow) * LDK + koff]);
#pragma unroll
    for (int nt = 0; nt < 8; ++nt) {
      short8 b = *reinterpret_cast<const short8*>(&sW[(nt * 16 + lrow) * LDK + koff]);
      acc[0][nt] = __builtin_amdgcn_mfma_f32_16x16x32_bf16(a0, b, acc[0][nt], 0, 0, 0);
      acc[1][nt] = __builtin_amdgcn_mfma_f32_16x16x32_bf16(a1, b, acc[1][nt], 0, 0, 0);
    }
  }

#pragma unroll
  for (int mt = 0; mt < 2; ++mt) {
    int rbase = n0 + wave * 32 + mt * 16 + quad * 4;
#pragma unroll
    for (int reg = 0; reg < 4; ++reg) {
      int r = rbase + reg;
      if (r < N) {
        float* op = out + (size_t)r * D + lrow;
#pragma unroll
        for (int nt = 0; nt < 8; ++nt)
          op[nt * 16] = acc[mt][nt][reg] + bv[nt];
      }
    }
  }
}

// ---------------------------------------------------------------------------
// fallback fp32-agg variants (R4-proven), cols-in-slots
// ---------------------------------------------------------------------------
__global__ __launch_bounds__(256) void k_agg(const float* __restrict__ x,
                                             const int* __restrict__ slots,
                                             float* __restrict__ agg,
                                             int N) {
  int wave = threadIdx.x >> 6;
  int lane = threadIdx.x & 63;
  int n = blockIdx.x * 4 + wave;
  if (n >= N) return;
  int c = -1;
  if (lane < KNB) c = slots[(size_t)n * KNB + lane];
  bool valid = (lane < KNB) && ((unsigned)c < (unsigned)N);
  unsigned long long m = __ballot(valid);
  int nsel = __popcll(m);
  float2 acc = make_float2(0.f, 0.f);
  if (nsel > 0) {
    unsigned long long mm = m;
    while (mm) {
      int j = (int)__builtin_ctzll(mm);
      mm &= mm - 1;
      int cj = __shfl(c, j);
      if ((unsigned)cj >= (unsigned)N) cj = 0;
      float2 v = reinterpret_cast<const float2*>(x + (size_t)cj * D)[lane];
      acc.x += v.x; acc.y += v.y;
    }
    float sc = 1.f / (float)nsel;
    acc.x *= sc; acc.y *= sc;
  } else {
    acc = reinterpret_cast<const float2*>(x + (size_t)n * D)[lane];
  }
  reinterpret_cast<float2*>(agg + (size_t)n * D)[lane] = acc;
}

// ---------------------------------------------------------------------------
// fallback fp32 VALU GEMM (R2/R4-proven, in-place safe)
// ---------------------------------------------------------------------------
#define BN 128
#define KC 32
#define LDP 132

__global__ __launch_bounds__(256) void k_gemm(const float* __restrict__ agg,
                                              const float* __restrict__ Wm,
                                              const float* __restrict__ bias,
                                              float* __restrict__ out, int N) {
  __shared__ float sA[KC][LDP];
  __shared__ float sW[KC][LDP];
  const int tid = threadIdx.x;
  const int tx = tid & 15;
  const int ty = tid >> 4;
  const int n0 = blockIdx.x * BN;

  float acc[8][8];
#pragma unroll
  for (int i = 0; i < 8; ++i)
#pragma unroll
    for (int j = 0; j < 8; ++j) acc[i][j] = 0.f;

  const int nl = tid >> 3;
  const int kq = tid & 7;

  for (int kc = 0; kc < D; kc += KC) {
#pragma unroll
    for (int i = 0; i < 4; ++i) {
      int rrow = nl + i * 32;
      int n = n0 + rrow;
      float4 av = make_float4(0.f, 0.f, 0.f, 0.f);
      if (n < N)
        av = reinterpret_cast<const float4*>(agg + (size_t)n * D + kc)[kq];
      int k = kq * 4;
      sA[k+0][rrow] = av.x; sA[k+1][rrow] = av.y;
      sA[k+2][rrow] = av.z; sA[k+3][rrow] = av.w;
      float4 wv = reinterpret_cast<const float4*>(Wm + (size_t)rrow * D + kc)[kq];
      sW[k+0][rrow] = wv.x; sW[k+1][rrow] = wv.y;
      sW[k+2][rrow] = wv.z; sW[k+3][rrow] = wv.w;
    }
    __syncthreads();
#pragma unroll
    for (int k = 0; k < KC; ++k) {
      float4 a0 = *reinterpret_cast<const float4*>(&sA[k][ty * 8]);
      float4 a1 = *reinterpret_cast<const float4*>(&sA[k][ty * 8 + 4]);
      float4 w0 = *reinterpret_cast<const float4*>(&sW[k][tx * 8]);
      float4 w1 = *reinterpret_cast<const float4*>(&sW[k][tx * 8 + 4]);
      float a[8] = {a0.x, a0.y, a0.z, a0.w, a1.x, a1.y, a1.z, a1.w};
      float w[8] = {w0.x, w0.y, w0.z, w0.w, w1.x, w1.y, w1.z, w1.w};
#pragma unroll
      for (int i = 0; i < 8; ++i)
#pragma unroll
        for (int j = 0; j < 8; ++j)
          acc[i][j] += a[i] * w[j];
    }
    __syncthreads();
  }

  float4 b0 = reinterpret_cast<const float4*>(bias)[tx * 2];
  float4 b1 = reinterpret_cast<const float4*>(bias)[tx * 2 + 1];
#pragma unroll
  for (int i = 0; i < 8; ++i) {
    int n = n0 + ty * 8 + i;
    if (n < N) {
      float4 v0 = make_float4(acc[i][0] + b0.x, acc[i][1] + b0.y,
                              acc[i][2] + b0.z, acc[i][3] + b0.w);
      float4 v1 = make_float4(acc[i][4] + b1.x, acc[i][5] + b1.y,
                              acc[i][6] + b1.z, acc[i][7] + b1.w);
      float4* op = reinterpret_cast<float4*>(out + (size_t)n * D + tx * 8);
      op[0] = v0;
      op[1] = v1;
    }
  }
}

// ---------------------------------------------------------------------------
extern "C" void kernel_launch(void* const* d_in, const int* in_sizes, int n_in,
                              void* d_out, int out_size, void* d_ws, size_t ws_size,
                              hipStream_t stream) {
  const float* x    = (const float*)d_in[0];
  const int*   ei   = (const int*)d_in[1];
  const float* Wm   = (const float*)d_in[2];
  const float* bias = (const float*)d_in[3];
  float* out = (float*)d_out;

  const int N = in_sizes[0] / D;
  const int E = in_sizes[1] / 2;

  // per-node capacity for the counting scatter; binned lives in d_out (dead
  // after k_select_flat). Sizes are ELEMENT counts -> out bytes = out_size*4.
  // caps = out_bytes/(N*8): bench 12.8e6*4/(1e5*8) = 64. (R5 bug: missed *4.)
  size_t out_bytes = (size_t)out_size * 4;
  int caps = (int)(out_bytes / ((size_t)N * 8));
  if (caps > CAPS) caps = CAPS;
  if (caps < 1) caps = 1;

  // ws layout: cur[N] | slots[N*10] | xh (N*256B)
  int* cur = (int*)d_ws;
  size_t off_slots = ((size_t)N * 4 + 15) & ~(size_t)15;
  int* slots = (int*)((char*)d_ws + off_slots);
  size_t off_xh = (off_slots + (size_t)N * KNB * 4 + 15) & ~(size_t)15;
  unsigned* xh = (unsigned*)((char*)d_ws + off_xh);

  const bool have_xh = ws_size >= off_xh + (size_t)N * D * 2;

  uint2* binned = (uint2*)d_out;
  const int zblocks = (N + 255) / 256;
  const int n8 = N * (D / 8);
  const int cblocks = have_xh ? (n8 + 255) / 256 : 0;

  k_xcast_zero<<<zblocks + cblocks, 256, 0, stream>>>(x, xh, n8, cur, N, zblocks);
  k_scatter<<<(E + 255) / 256, 256, 0, stream>>>(ei, ei + E, E, N, caps, cur, binned);
  k_select_flat<<<(N + 255) / 256, 256, 0, stream>>>(binned, cur, slots, N, E, caps);

  if (have_xh) {
    k_fused<<<(N + GBN - 1) / GBN, 256, 0, stream>>>(xh, x, slots, Wm, bias, out, N);
  } else {
    k_agg<<<(N + 3) / 4, 256, 0, stream>>>(x, slots, out, N);
    k_gemm<<<(N + BN - 1) / BN, 256, 0, stream>>>(out, Wm, bias, out, N);
  }
}

// Round 8
// 290.306 us; speedup vs baseline: 1.0007x; 1.0007x over previous
//
#include <hip/hip_runtime.h>
#include <hip/hip_bf16.h>
#include <cstdint>
#include <cstddef>

#define D 128           // feature dim
#define KNB 10          // NUM_NEIGHBORS
#define SENT 0x7FFFFFFF
#define SHIFT 7         // nodes per bucket = 128
#define NPB 128
#define T_BIN 256
#define EPB 16384       // edges per binning block (R13: 4096->16384, longer runs)
#define MAXNB 1024
#define SCAP 64         // per-node candidate cap (P(deg>=64|lam=16)~1e-19)
#define SELPAD 65       // +1 pad: bin[rl][k] read spreads over 16 banks not 1

typedef __attribute__((ext_vector_type(8))) short short8;   // MFMA A/B frag (8 bf16)
typedef __attribute__((ext_vector_type(4))) float floatx4;  // MFMA C/D frag

__device__ inline unsigned bf16_rne(float f) {
  unsigned u = __builtin_bit_cast(unsigned, f);
  return (u + 0x7FFFu + ((u >> 16) & 1u)) >> 16;
}
__device__ inline float bflo(unsigned u) { return __builtin_bit_cast(float, u << 16); }
__device__ inline float bfhi(unsigned u) { return __builtin_bit_cast(float, u & 0xFFFF0000u); }

// ---------------------------------------------------------------------------
// k_init: counts[0..NB)=0. Separate launch: zeroing must complete before any
// count_xcast bin-block flushes its histogram (same-kernel zeroing races).
// ---------------------------------------------------------------------------
__global__ __launch_bounds__(256) void k_init(int* __restrict__ counts, int NB) {
  int i = blockIdx.x * 256 + threadIdx.x;
  if (i < NB) counts[i] = 0;
}

// ---------------------------------------------------------------------------
// k_count_xcast: blocks [0,blocks_bin) do the LDS-histogram edge count;
// blocks [blocks_bin,..) stream-cast x fp32 -> xh bf16 pairs (overlapped).
// (R2/R4-verified structure; EPB now 16384.)
// ---------------------------------------------------------------------------
__global__ __launch_bounds__(T_BIN) void k_count_xcast(const int* __restrict__ row, int E,
                                                       int NB, int* __restrict__ counts,
                                                       int blocks_bin,
                                                       const float* __restrict__ x,
                                                       unsigned* __restrict__ xh, int n8) {
  if ((int)blockIdx.x < blocks_bin) {
    __shared__ int hist[MAXNB];
    for (int i = threadIdx.x; i < NB; i += T_BIN) hist[i] = 0;
    __syncthreads();
    int e0 = blockIdx.x * EPB;
    for (int i = threadIdx.x; i < EPB; i += T_BIN) {
      int e = e0 + i;
      if (e < E) atomicAdd(&hist[row[e] >> SHIFT], 1);
    }
    __syncthreads();
    for (int i = threadIdx.x; i < NB; i += T_BIN)
      if (hist[i]) atomicAdd(&counts[i], hist[i]);
  } else {
    int t = ((int)blockIdx.x - blocks_bin) * T_BIN + threadIdx.x;
    if (t >= n8) return;
    const float4* p = reinterpret_cast<const float4*>(x) + (size_t)t * 2;
    float4 a = p[0], b = p[1];
    uint4 o;
    o.x = bf16_rne(a.x) | (bf16_rne(a.y) << 16);
    o.y = bf16_rne(a.z) | (bf16_rne(a.w) << 16);
    o.z = bf16_rne(b.x) | (bf16_rne(b.y) << 16);
    o.w = bf16_rne(b.z) | (bf16_rne(b.w) << 16);
    reinterpret_cast<uint4*>(xh)[t] = o;
  }
}

// ---------------------------------------------------------------------------
__global__ __launch_bounds__(MAXNB) void k_scan(const int* __restrict__ counts, int NB,
                                                int* __restrict__ bases,
                                                int* __restrict__ cursor) {
  __shared__ int buf[MAXNB];
  int t = threadIdx.x;
  int v = (t < NB) ? counts[t] : 0;
  buf[t] = v;
  __syncthreads();
  for (int off = 1; off < MAXNB; off <<= 1) {
    int xv = (t >= off) ? buf[t - off] : 0;
    __syncthreads();
    buf[t] += xv;
    __syncthreads();
  }
  if (t < NB) {
    int base = buf[t] - v;
    bases[t] = base;
    cursor[t] = base;
  }
}

// ---------------------------------------------------------------------------
// k_scatter2: partition edges into bucket segments. 64-bit entries {tag,col},
// tag = (r&127)<<24 | eid (E < 2^24); col streamed coalesced HERE (R9-verified)
// so no later kernel random-gathers ei. Writes are per-(block,bucket)
// CONTIGUOUS runs (~21 entries = 168B at EPB 16384) — this is the write-
// coalescing the R10-R12 direct scatter lacked (R6/R7 lesson: random 8B
// scatters cost a 64B line each; runs amortize it).
// ---------------------------------------------------------------------------
__global__ __launch_bounds__(T_BIN) void k_scatter2(const int* __restrict__ row,
                                                    const int* __restrict__ col, int E,
                                                    int NB, int* __restrict__ cursor,
                                                    uint2* __restrict__ binned) {
  __shared__ int hist[MAXNB];
  __shared__ int lbase[MAXNB];
  for (int i = threadIdx.x; i < NB; i += T_BIN) hist[i] = 0;
  __syncthreads();
  int e0 = blockIdx.x * EPB;
  for (int i = threadIdx.x; i < EPB; i += T_BIN) {
    int e = e0 + i;
    if (e < E) atomicAdd(&hist[row[e] >> SHIFT], 1);
  }
  __syncthreads();
  for (int i = threadIdx.x; i < NB; i += T_BIN) {
    int h = hist[i];
    lbase[i] = h ? atomicAdd(&cursor[i], h) : 0;
  }
  __syncthreads();
  for (int i = threadIdx.x; i < NB; i += T_BIN) hist[i] = 0;  // reuse as cursor
  __syncthreads();
  for (int i = threadIdx.x; i < EPB; i += T_BIN) {
    int e = e0 + i;
    if (e < E) {
      int r = row[e];
      int b = r >> SHIFT;
      int pos = lbase[b] + atomicAdd(&hist[b], 1);
      binned[pos] = make_uint2(((unsigned)(r & (NPB - 1)) << 24) | (unsigned)e,
                               (unsigned)col[e]);
    }
  }
}

// ---------------------------------------------------------------------------
// k_select_bucket: R13 — replaces the R2 LDS atomicMin-CASCADE (~7 returning
// atomics/edge, ~11M serialized — the measured-by-elimination ~45 µs) with:
//  phase 1: LDS counting-scatter — ONE returning atomicAdd per edge, entry
//           dropped into bin[rl][k] (cap 64, same hardening as R7-R12).
//  phase 2: threads 0..127 run the R7-proven branchless register top-10
//           compare-swap chain over their node's <=64 LDS candidates
//           (key = eid = tag&0xFFFFFF; payload col carried alongside).
// Selected set = 10 smallest eids — deterministic regardless of atomic
// arrival order => downstream arithmetic bit-identical.
// LDS 67 KB -> 2 WGs/CU. SELPAD=65 spreads phase-2 reads over 16 banks.
// HARDENING: base/cnt clamped to [0,E]; rl masked; k capped; slot valid iff
// e10[k] < E (rejects 0xFFFFFFFF init/poison); consumer re-checks col < N.
// ---------------------------------------------------------------------------
__global__ __launch_bounds__(256) void k_select_bucket(const uint2* __restrict__ binned,
                                                       const int* __restrict__ bases,
                                                       const int* __restrict__ counts,
                                                       int* __restrict__ slots_g,
                                                       int N, int E) {
  __shared__ uint2 bin[NPB][SELPAD];
  __shared__ int cur[NPB];
  int b = blockIdx.x;
  int nbase = b << SHIFT;
  int nloc = min(NPB, N - nbase);
  for (int i = threadIdx.x; i < NPB; i += 256) cur[i] = 0;
  __syncthreads();

  int base = bases[b];
  int cnt = counts[b];
  if (base < 0) base = 0;
  if (base > E) base = E;
  if (cnt < 0) cnt = 0;
  if (cnt > E - base) cnt = E - base;

  for (int i = threadIdx.x; i < cnt; i += 256) {
    uint2 en = binned[base + i];
    int rl = (int)(en.x >> 24) & (NPB - 1);
    int k = atomicAdd(&cur[rl], 1);
    if (k < SCAP) bin[rl][k] = en;
  }
  __syncthreads();

  int rl = threadIdx.x;
  if (rl < nloc) {
    int c = min(cur[rl], SCAP);
    unsigned e10[KNB], c10[KNB];
#pragma unroll
    for (int k = 0; k < KNB; ++k) { e10[k] = 0xFFFFFFFFu; c10[k] = 0xFFFFFFFFu; }
    for (int k = 0; k < c; ++k) {
      uint2 en = bin[rl][k];
      unsigned ev = en.x & 0xFFFFFFu, cv = en.y;
#pragma unroll
      for (int j = 0; j < KNB; ++j) {
        bool lt = ev < e10[j];
        unsigned te = lt ? e10[j] : ev;
        unsigned tc = lt ? c10[j] : cv;
        e10[j] = lt ? ev : e10[j];
        c10[j] = lt ? cv : c10[j];
        ev = te; cv = tc;
      }
    }
#pragma unroll
    for (int k = 0; k < KNB; ++k)
      slots_g[(size_t)(nbase + rl) * KNB + k] =
          (e10[k] < (unsigned)E) ? (int)c10[k] : -1;
  }
}

// ---------------------------------------------------------------------------
// k_fused: aggregation + GEMM in ONE kernel (R8-verified: 62 µs = traffic
// floor 214 MB at the ~3.5 TB/s random-granule ceiling; occupancy-
// insensitive — UNCHANGED).
// ---------------------------------------------------------------------------
#define GBN 128
#define LDK 136

__global__ __launch_bounds__(256) void k_fused(const unsigned* __restrict__ xh,
                                               const float* __restrict__ x,
                                               const int* __restrict__ slots,
                                               const float* __restrict__ Wm,
                                               const float* __restrict__ bias,
                                               float* __restrict__ out, int N) {
  __shared__ unsigned short sA[GBN * LDK];
  __shared__ unsigned short sW[GBN * LDK];
  const int tid = threadIdx.x;
  const int n0 = blockIdx.x * GBN;

  // ---- phase W: W fp32 -> bf16 into sW ----
#pragma unroll
  for (int i = 0; i < 16; ++i) {
    int q = i * 256 + tid;
    int row = q >> 5;
    int c4 = q & 31;
    float4 wv = reinterpret_cast<const float4*>(Wm + (size_t)row * D)[c4];
    ushort4 uw;
    uw.x = (unsigned short)bf16_rne(wv.x);
    uw.y = (unsigned short)bf16_rne(wv.y);
    uw.z = (unsigned short)bf16_rne(wv.z);
    uw.w = (unsigned short)bf16_rne(wv.w);
    *reinterpret_cast<ushort4*>(&sW[row * LDK + c4 * 4]) = uw;
  }

  // ---- phase G: aggregate 8 nodes per 16-lane group, write A-tile ----
  const int lane = tid & 63;
  const int j16 = lane & 15;       // dim-octet index within the 256B row
  const int gsh = lane & 48;       // group base lane within wave
  const int grp = tid >> 4;        // 0..15

  const uint4* xh4 = reinterpret_cast<const uint4*>(xh);

  for (int nn = 0; nn < 8; ++nn) {
    const int row = nn * 16 + grp;         // 0..127
    const int n = n0 + row;
    const bool active = n < N;

    int scol = -1;
    if (active && j16 < KNB) scol = slots[(size_t)n * KNB + j16];
    bool valid = (unsigned)scol < (unsigned)N;
    unsigned long long bal = __ballot(valid);
    int nsel = __popc((unsigned)((bal >> gsh) & 0xFFFFull));

    // broadcast the group's 10 cols, then 10 independent 16B gathers
    int ck[KNB];
#pragma unroll
    for (int k = 0; k < KNB; ++k) ck[k] = __shfl(scol, gsh + k);

    uint4 uu[KNB];
    float wj[KNB];
#pragma unroll
    for (int k = 0; k < KNB; ++k) {
      bool vk = (unsigned)ck[k] < (unsigned)N;
      wj[k] = vk ? 1.f : 0.f;
      uu[k] = xh4[(size_t)(vk ? ck[k] : 0) * 16 + j16];
    }

    float acc[8];
#pragma unroll
    for (int q = 0; q < 8; ++q) acc[q] = 0.f;

    if (active) {
      if (nsel > 0) {
#pragma unroll
        for (int k = 0; k < KNB; ++k) {
          float w = wj[k];
          acc[0] += w * bflo(uu[k].x); acc[1] += w * bfhi(uu[k].x);
          acc[2] += w * bflo(uu[k].y); acc[3] += w * bfhi(uu[k].y);
          acc[4] += w * bflo(uu[k].z); acc[5] += w * bfhi(uu[k].z);
          acc[6] += w * bflo(uu[k].w); acc[7] += w * bfhi(uu[k].w);
        }
        float sc = 1.f / (float)nsel;
#pragma unroll
        for (int q = 0; q < 8; ++q) acc[q] *= sc;
      } else {
        const float4* xr = reinterpret_cast<const float4*>(x + (size_t)n * D);
        float4 v0 = xr[j16 * 2], v1 = xr[j16 * 2 + 1];
        acc[0] = v0.x; acc[1] = v0.y; acc[2] = v0.z; acc[3] = v0.w;
        acc[4] = v1.x; acc[5] = v1.y; acc[6] = v1.z; acc[7] = v1.w;
      }
    }

    ushort4 ow;
    ow.x = (unsigned short)bf16_rne(acc[0]);
    ow.y = (unsigned short)bf16_rne(acc[1]);
    ow.z = (unsigned short)bf16_rne(acc[2]);
    ow.w = (unsigned short)bf16_rne(acc[3]);
    ushort4 ow2;
    ow2.x = (unsigned short)bf16_rne(acc[4]);
    ow2.y = (unsigned short)bf16_rne(acc[5]);
    ow2.z = (unsigned short)bf16_rne(acc[6]);
    ow2.w = (unsigned short)bf16_rne(acc[7]);
    *reinterpret_cast<ushort4*>(&sA[row * LDK + j16 * 8]) = ow;
    *reinterpret_cast<ushort4*>(&sA[row * LDK + j16 * 8 + 4]) = ow2;
  }
  __syncthreads();

  // ---- phase M: verified MFMA body (frag layouts HW-verified m89) ----
  const int wave = tid >> 6;
  const int lrow = lane & 15;
  const int quad = lane >> 4;

  floatx4 acc[2][8];
#pragma unroll
  for (int mt = 0; mt < 2; ++mt)
#pragma unroll
    for (int nt = 0; nt < 8; ++nt)
      acc[mt][nt] = (floatx4){0.f, 0.f, 0.f, 0.f};

  float bv[8];
#pragma unroll
  for (int nt = 0; nt < 8; ++nt) bv[nt] = bias[nt * 16 + lrow];

#pragma unroll
  for (int ks = 0; ks < 4; ++ks) {
    int koff = ks * 32 + quad * 8;
    short8 a0 = *reinterpret_cast<const short8*>(&sA[(wave * 32 + lrow) * LDK + koff]);
    short8 a1 = *reinterpret_cast<const short8*>(&sA[(wave * 32 + 16 + lrow) * LDK + koff]);
#pragma unroll
    for (int nt = 0; nt < 8; ++nt) {
      short8 b = *reinterpret_cast<const short8*>(&sW[(nt * 16 + lrow) * LDK + koff]);
      acc[0][nt] = __builtin_amdgcn_mfma_f32_16x16x32_bf16(a0, b, acc[0][nt], 0, 0, 0);
      acc[1][nt] = __builtin_amdgcn_mfma_f32_16x16x32_bf16(a1, b, acc[1][nt], 0, 0, 0);
    }
  }

#pragma unroll
  for (int mt = 0; mt < 2; ++mt) {
    int rbase = n0 + wave * 32 + mt * 16 + quad * 4;
#pragma unroll
    for (int reg = 0; reg < 4; ++reg) {
      int r = rbase + reg;
      if (r < N) {
        float* op = out + (size_t)r * D + lrow;
#pragma unroll
        for (int nt = 0; nt < 8; ++nt)
          op[nt * 16] = acc[mt][nt][reg] + bv[nt];
      }
    }
  }
}

// ---------------------------------------------------------------------------
// fallback fp32-agg variants (R4-proven), cols-in-slots
// ---------------------------------------------------------------------------
__global__ __launch_bounds__(256) void k_agg(const float* __restrict__ x,
                                             const int* __restrict__ slots,
                                             float* __restrict__ agg,
                                             int N) {
  int wave = threadIdx.x >> 6;
  int lane = threadIdx.x & 63;
  int n = blockIdx.x * 4 + wave;
  if (n >= N) return;
  int c = -1;
  if (lane < KNB) c = slots[(size_t)n * KNB + lane];
  bool valid = (lane < KNB) && ((unsigned)c < (unsigned)N);
  unsigned long long m = __ballot(valid);
  int nsel = __popcll(m);
  float2 acc = make_float2(0.f, 0.f);
  if (nsel > 0) {
    unsigned long long mm = m;
    while (mm) {
      int j = (int)__builtin_ctzll(mm);
      mm &= mm - 1;
      int cj = __shfl(c, j);
      if ((unsigned)cj >= (unsigned)N) cj = 0;
      float2 v = reinterpret_cast<const float2*>(x + (size_t)cj * D)[lane];
      acc.x += v.x; acc.y += v.y;
    }
    float sc = 1.f / (float)nsel;
    acc.x *= sc; acc.y *= sc;
  } else {
    acc = reinterpret_cast<const float2*>(x + (size_t)n * D)[lane];
  }
  reinterpret_cast<float2*>(agg + (size_t)n * D)[lane] = acc;
}

// ---------------------------------------------------------------------------
// fallback fp32 VALU GEMM (R2/R4-proven, in-place safe)
// ---------------------------------------------------------------------------
#define BN 128
#define KC 32
#define LDP 132

__global__ __launch_bounds__(256) void k_gemm(const float* __restrict__ agg,
                                              const float* __restrict__ Wm,
                                              const float* __restrict__ bias,
                                              float* __restrict__ out, int N) {
  __shared__ float sA[KC][LDP];
  __shared__ float sW[KC][LDP];
  const int tid = threadIdx.x;
  const int tx = tid & 15;
  const int ty = tid >> 4;
  const int n0 = blockIdx.x * BN;

  float acc[8][8];
#pragma unroll
  for (int i = 0; i < 8; ++i)
#pragma unroll
    for (int j = 0; j < 8; ++j) acc[i][j] = 0.f;

  const int nl = tid >> 3;
  const int kq = tid & 7;

  for (int kc = 0; kc < D; kc += KC) {
#pragma unroll
    for (int i = 0; i < 4; ++i) {
      int rrow = nl + i * 32;
      int n = n0 + rrow;
      float4 av = make_float4(0.f, 0.f, 0.f, 0.f);
      if (n < N)
        av = reinterpret_cast<const float4*>(agg + (size_t)n * D + kc)[kq];
      int k = kq * 4;
      sA[k+0][rrow] = av.x; sA[k+1][rrow] = av.y;
      sA[k+2][rrow] = av.z; sA[k+3][rrow] = av.w;
      float4 wv = reinterpret_cast<const float4*>(Wm + (size_t)rrow * D + kc)[kq];
      sW[k+0][rrow] = wv.x; sW[k+1][rrow] = wv.y;
      sW[k+2][rrow] = wv.z; sW[k+3][rrow] = wv.w;
    }
    __syncthreads();
#pragma unroll
    for (int k = 0; k < KC; ++k) {
      float4 a0 = *reinterpret_cast<const float4*>(&sA[k][ty * 8]);
      float4 a1 = *reinterpret_cast<const float4*>(&sA[k][ty * 8 + 4]);
      float4 w0 = *reinterpret_cast<const float4*>(&sW[k][tx * 8]);
      float4 w1 = *reinterpret_cast<const float4*>(&sW[k][tx * 8 + 4]);
      float a[8] = {a0.x, a0.y, a0.z, a0.w, a1.x, a1.y, a1.z, a1.w};
      float w[8] = {w0.x, w0.y, w0.z, w0.w, w1.x, w1.y, w1.z, w1.w};
#pragma unroll
      for (int i = 0; i < 8; ++i)
#pragma unroll
        for (int j = 0; j < 8; ++j)
          acc[i][j] += a[i] * w[j];
    }
    __syncthreads();
  }

  float4 b0 = reinterpret_cast<const float4*>(bias)[tx * 2];
  float4 b1 = reinterpret_cast<const float4*>(bias)[tx * 2 + 1];
#pragma unroll
  for (int i = 0; i < 8; ++i) {
    int n = n0 + ty * 8 + i;
    if (n < N) {
      float4 v0 = make_float4(acc[i][0] + b0.x, acc[i][1] + b0.y,
                              acc[i][2] + b0.z, acc[i][3] + b0.w);
      float4 v1 = make_float4(acc[i][4] + b1.x, acc[i][5] + b1.y,
                              acc[i][6] + b1.z, acc[i][7] + b1.w);
      float4* op = reinterpret_cast<float4*>(out + (size_t)n * D + tx * 8);
      op[0] = v0;
      op[1] = v1;
    }
  }
}

// ---------------------------------------------------------------------------
extern "C" void kernel_launch(void* const* d_in, const int* in_sizes, int n_in,
                              void* d_out, int out_size, void* d_ws, size_t ws_size,
                              hipStream_t stream) {
  const float* x    = (const float*)d_in[0];
  const int*   ei   = (const int*)d_in[1];
  const float* Wm   = (const float*)d_in[2];
  const float* bias = (const float*)d_in[3];
  float* out = (float*)d_out;

  const int N = in_sizes[0] / D;
  const int E = in_sizes[1] / 2;
  const int NB = (N + NPB - 1) >> SHIFT;

  // ws layout: counts|bases|cursor (3*NB) | slots[N*10] | xh (N*256B)
  int* counts = (int*)d_ws;
  int* bases  = counts + NB;
  int* cursor = bases + NB;
  size_t off_slots = ((size_t)(3 * NB) * 4 + 15) & ~(size_t)15;
  int* slots = (int*)((char*)d_ws + off_slots);
  size_t off_xh = (off_slots + (size_t)N * KNB * 4 + 15) & ~(size_t)15;
  unsigned* xh = (unsigned*)((char*)d_ws + off_xh);

  const bool have_xh = ws_size >= off_xh + (size_t)N * D * 2;

  uint2* binned = (uint2*)d_out;  // staged in d_out (E*8 B = 12.8 MB <= 51.2 MB),
                                  // dead after k_select_bucket
  const int blocks_bin = (E + EPB - 1) / EPB;
  const int n8 = N * (D / 8);
  const int xblocks = have_xh ? (n8 + T_BIN - 1) / T_BIN : 0;

  k_init<<<(NB + 255) / 256, 256, 0, stream>>>(counts, NB);
  k_count_xcast<<<blocks_bin + xblocks, T_BIN, 0, stream>>>(ei, E, NB, counts,
                                                            blocks_bin, x, xh, n8);
  k_scan<<<1, MAXNB, 0, stream>>>(counts, NB, bases, cursor);
  k_scatter2<<<blocks_bin, T_BIN, 0, stream>>>(ei, ei + E, E, NB, cursor, binned);
  k_select_bucket<<<NB, 256, 0, stream>>>(binned, bases, counts, slots, N, E);

  if (have_xh) {
    k_fused<<<(N + GBN - 1) / GBN, 256, 0, stream>>>(xh, x, slots, Wm, bias, out, N);
  } else {
    k_agg<<<(N + 3) / 4, 256, 0, stream>>>(x, slots, out, N);
    k_gemm<<<(N + BN - 1) / BN, 256, 0, stream>>>(out, Wm, bias, out, N);
  }
}

// Round 9
// 215.712 us; speedup vs baseline: 1.3467x; 1.3458x over previous
//
#include <hip/hip_runtime.h>
#include <hip/hip_bf16.h>
#include <cstdint>
#include <cstddef>

#define D 128           // feature dim
#define KNB 10          // NUM_NEIGHBORS
#define SHIFT 7         // nodes per bucket = 128 == GBN (bucket == fused tile)
#define NPB 128
#define T_BIN 256
#define EPB 4096        // R14: back to 4096 (R8: 16384 -> 98 blocks, write-latency bound)
#define MAXNB 1024
#define SCAP 64         // per-node candidate cap (bench max degree ~48)
#define SELPAD 65       // odd dword stride -> conflict-free per-thread chain reads
#define CAPB 4096       // per-bucket region capacity (load ~2048 +- 6sig*45 << 4096)
#define GBN 128
#define LDK 136

typedef __attribute__((ext_vector_type(8))) short short8;   // MFMA A/B frag (8 bf16)
typedef __attribute__((ext_vector_type(4))) float floatx4;  // MFMA C/D frag

__device__ inline unsigned bf16_rne(float f) {
  unsigned u = __builtin_bit_cast(unsigned, f);
  return (u + 0x7FFFu + ((u >> 16) & 1u)) >> 16;
}
__device__ inline float bflo(unsigned u) { return __builtin_bit_cast(float, u << 16); }
__device__ inline float bfhi(unsigned u) { return __builtin_bit_cast(float, u & 0xFFFF0000u); }

// ---------------------------------------------------------------------------
// k_scatter_xcast: blocks [0,blocks_bin): partition edges into FIXED per-
// bucket regions binned[b*capb ..] — no count pass, no scan. Per-(block,
// bucket) run gets base = atomicAdd(gcur[b], h) (one global atomic per run,
// ~300k total), then LDS-cursor rescatter -> CONTIGUOUS run writes (R8-
// verified: coalesced runs cut WRITE_SIZE 99.5->18.5 MB; R14 reverts EPB to
// 4096 for 391 blocks of store parallelism — R8's 98 blocks were latency-
// bound at 0.3 TB/s). Blocks [blocks_bin,..): stream-cast x fp32 -> xh bf16.
// HARDENING: pos < capb clamp (drop only in astronomically-impossible
// overflow); consumer re-validates every entry.
// ---------------------------------------------------------------------------
__global__ __launch_bounds__(T_BIN) void k_scatter_xcast(const int* __restrict__ row,
                                                         const int* __restrict__ col,
                                                         int E, int NB, int capb,
                                                         int* __restrict__ gcur,
                                                         uint2* __restrict__ binned,
                                                         int blocks_bin,
                                                         const float* __restrict__ x,
                                                         unsigned* __restrict__ xh,
                                                         int n8) {
  if ((int)blockIdx.x < blocks_bin) {
    __shared__ int hist[MAXNB];
    __shared__ int lbase[MAXNB];
    for (int i = threadIdx.x; i < NB; i += T_BIN) hist[i] = 0;
    __syncthreads();
    int e0 = blockIdx.x * EPB;
    for (int i = threadIdx.x; i < EPB; i += T_BIN) {
      int e = e0 + i;
      if (e < E) atomicAdd(&hist[row[e] >> SHIFT], 1);
    }
    __syncthreads();
    for (int i = threadIdx.x; i < NB; i += T_BIN) {
      int h = hist[i];
      lbase[i] = h ? atomicAdd(&gcur[i], h) : 0;
    }
    __syncthreads();
    for (int i = threadIdx.x; i < NB; i += T_BIN) hist[i] = 0;  // reuse as cursor
    __syncthreads();
    for (int i = threadIdx.x; i < EPB; i += T_BIN) {
      int e = e0 + i;
      if (e < E) {
        int r = row[e];
        int b = r >> SHIFT;
        int pos = lbase[b] + atomicAdd(&hist[b], 1);
        if (pos < capb)
          binned[(size_t)b * capb + pos] =
              make_uint2(((unsigned)(r & (NPB - 1)) << 24) | (unsigned)e,
                         (unsigned)col[e]);
      }
    }
  } else {
    int t = ((int)blockIdx.x - blocks_bin) * T_BIN + threadIdx.x;
    if (t >= n8) return;
    const float4* p = reinterpret_cast<const float4*>(x) + (size_t)t * 2;
    float4 a = p[0], b = p[1];
    uint4 o;
    o.x = bf16_rne(a.x) | (bf16_rne(a.y) << 16);
    o.y = bf16_rne(a.z) | (bf16_rne(a.w) << 16);
    o.z = bf16_rne(b.x) | (bf16_rne(b.y) << 16);
    o.w = bf16_rne(b.z) | (bf16_rne(b.w) << 16);
    reinterpret_cast<uint4*>(xh)[t] = o;
  }
}

// ---------------------------------------------------------------------------
// k_fused: R14 — select + aggregate + GEMM in ONE kernel. Exploits bucket
// (SHIFT=7, 128 nodes) == fused tile (GBN=128): block b selects from its own
// binned region, so slots never round-trip through global (8 MB saved) and
// two launch boundaries disappear.
//  phase S: LDS counting-scatter of <=cnt entries into split binE/binC
//           (SELPAD=65: odd dword stride -> the per-thread chain reads are
//           2-way-free); 128 threads run the R7-proven branchless register
//           top-10 by eid; slots_l[128*10] <- col or -1. bin arena UNIONs
//           with sA/sW (dead after slots_l, barrier-separated).
//  phase W: stage W fp32->bf16 into sW.
//  phase G: 16 16-lane groups x 8 nodes: 10 col-broadcasts + 10 independent
//           uint4 bf16 gathers, fp32 mean, pack -> sA (R8-verified floor).
//  phase M: verified 16x16x32 bf16 MFMA body, bias add, fp32 out.
// HARDENING: cnt clamped [0,capb]; rl masked; k capped; slot valid iff
// eid < E; phase G re-checks col < N before indexing xh.
// ---------------------------------------------------------------------------
__global__ __launch_bounds__(256) void k_fused(const unsigned* __restrict__ xh,
                                               const float* __restrict__ x,
                                               const uint2* __restrict__ binned,
                                               const int* __restrict__ gcur, int capb,
                                               const float* __restrict__ Wm,
                                               const float* __restrict__ bias,
                                               float* __restrict__ out, int N, int E) {
  __shared__ int slots_l[GBN * KNB];                      // 5120 B, survives phases
  __shared__ __align__(16) char uni[GBN * LDK * 2 * 2];   // 69632 B arena
  unsigned* binE = reinterpret_cast<unsigned*>(uni);      // [GBN*SELPAD] 33280 B
  unsigned* binC = binE + GBN * SELPAD;                   // 33280 B
  int* scur = reinterpret_cast<int*>(binC + GBN * SELPAD);// 512 B (<= 69632 total)
  unsigned short* sA = reinterpret_cast<unsigned short*>(uni);
  unsigned short* sW = sA + GBN * LDK;

  const int tid = threadIdx.x;
  const int b = blockIdx.x;
  const int n0 = b * GBN;

  // ---- phase S: per-bucket top-10 selection ----
  for (int i = tid; i < GBN; i += 256) scur[i] = 0;
  __syncthreads();
  int cnt = gcur[b];
  cnt = min(max(cnt, 0), capb);
  for (int i = tid; i < cnt; i += 256) {
    uint2 en = binned[(size_t)b * capb + i];
    int rl = (int)(en.x >> 24) & (GBN - 1);
    int k = atomicAdd(&scur[rl], 1);
    if (k < SCAP) {
      binE[rl * SELPAD + k] = en.x;
      binC[rl * SELPAD + k] = en.y;
    }
  }
  __syncthreads();
  if (tid < GBN) {
    int c = min(scur[tid], SCAP);
    unsigned e10[KNB], c10[KNB];
#pragma unroll
    for (int k = 0; k < KNB; ++k) { e10[k] = 0xFFFFFFFFu; c10[k] = 0xFFFFFFFFu; }
    for (int k = 0; k < c; ++k) {
      unsigned ev = binE[tid * SELPAD + k] & 0xFFFFFFu;
      unsigned cv = binC[tid * SELPAD + k];
#pragma unroll
      for (int j = 0; j < KNB; ++j) {
        bool lt = ev < e10[j];
        unsigned te = lt ? e10[j] : ev;
        unsigned tc = lt ? c10[j] : cv;
        e10[j] = lt ? ev : e10[j];
        c10[j] = lt ? cv : c10[j];
        ev = te; cv = tc;
      }
    }
#pragma unroll
    for (int k = 0; k < KNB; ++k)
      slots_l[tid * KNB + k] = (e10[k] < (unsigned)E) ? (int)c10[k] : -1;
  }
  __syncthreads();   // bin arena dead; safe to overwrite as sA/sW

  // ---- phase W: W fp32 -> bf16 into sW ----
#pragma unroll
  for (int i = 0; i < 16; ++i) {
    int q = i * 256 + tid;
    int row = q >> 5;
    int c4 = q & 31;
    float4 wv = reinterpret_cast<const float4*>(Wm + (size_t)row * D)[c4];
    ushort4 uw;
    uw.x = (unsigned short)bf16_rne(wv.x);
    uw.y = (unsigned short)bf16_rne(wv.y);
    uw.z = (unsigned short)bf16_rne(wv.z);
    uw.w = (unsigned short)bf16_rne(wv.w);
    *reinterpret_cast<ushort4*>(&sW[row * LDK + c4 * 4]) = uw;
  }

  // ---- phase G: aggregate 8 nodes per 16-lane group, write A-tile ----
  const int lane = tid & 63;
  const int j16 = lane & 15;       // dim-octet index within the 256B row
  const int gsh = lane & 48;       // group base lane within wave
  const int grp = tid >> 4;        // 0..15

  const uint4* xh4 = reinterpret_cast<const uint4*>(xh);

  for (int nn = 0; nn < 8; ++nn) {
    const int row = nn * 16 + grp;         // 0..127
    const int n = n0 + row;
    const bool active = n < N;

    int scol = -1;
    if (active && j16 < KNB) scol = slots_l[row * KNB + j16];
    bool valid = (unsigned)scol < (unsigned)N;
    unsigned long long bal = __ballot(valid);
    int nsel = __popc((unsigned)((bal >> gsh) & 0xFFFFull));

    // broadcast the group's 10 cols, then 10 independent 16B gathers
    int ck[KNB];
#pragma unroll
    for (int k = 0; k < KNB; ++k) ck[k] = __shfl(scol, gsh + k);

    uint4 uu[KNB];
    float wj[KNB];
#pragma unroll
    for (int k = 0; k < KNB; ++k) {
      bool vk = (unsigned)ck[k] < (unsigned)N;
      wj[k] = vk ? 1.f : 0.f;
      uu[k] = xh4[(size_t)(vk ? ck[k] : 0) * 16 + j16];
    }

    float acc[8];
#pragma unroll
    for (int q = 0; q < 8; ++q) acc[q] = 0.f;

    if (active) {
      if (nsel > 0) {
#pragma unroll
        for (int k = 0; k < KNB; ++k) {
          float w = wj[k];
          acc[0] += w * bflo(uu[k].x); acc[1] += w * bfhi(uu[k].x);
          acc[2] += w * bflo(uu[k].y); acc[3] += w * bfhi(uu[k].y);
          acc[4] += w * bflo(uu[k].z); acc[5] += w * bfhi(uu[k].z);
          acc[6] += w * bflo(uu[k].w); acc[7] += w * bfhi(uu[k].w);
        }
        float sc = 1.f / (float)nsel;
#pragma unroll
        for (int q = 0; q < 8; ++q) acc[q] *= sc;
      } else {
        const float4* xr = reinterpret_cast<const float4*>(x + (size_t)n * D);
        float4 v0 = xr[j16 * 2], v1 = xr[j16 * 2 + 1];
        acc[0] = v0.x; acc[1] = v0.y; acc[2] = v0.z; acc[3] = v0.w;
        acc[4] = v1.x; acc[5] = v1.y; acc[6] = v1.z; acc[7] = v1.w;
      }
    }

    ushort4 ow;
    ow.x = (unsigned short)bf16_rne(acc[0]);
    ow.y = (unsigned short)bf16_rne(acc[1]);
    ow.z = (unsigned short)bf16_rne(acc[2]);
    ow.w = (unsigned short)bf16_rne(acc[3]);
    ushort4 ow2;
    ow2.x = (unsigned short)bf16_rne(acc[4]);
    ow2.y = (unsigned short)bf16_rne(acc[5]);
    ow2.z = (unsigned short)bf16_rne(acc[6]);
    ow2.w = (unsigned short)bf16_rne(acc[7]);
    *reinterpret_cast<ushort4*>(&sA[row * LDK + j16 * 8]) = ow;
    *reinterpret_cast<ushort4*>(&sA[row * LDK + j16 * 8 + 4]) = ow2;
  }
  __syncthreads();

  // ---- phase M: verified MFMA body (frag layouts HW-verified m89) ----
  const int wave = tid >> 6;
  const int lrow = lane & 15;
  const int quad = lane >> 4;

  floatx4 acc[2][8];
#pragma unroll
  for (int mt = 0; mt < 2; ++mt)
#pragma unroll
    for (int nt = 0; nt < 8; ++nt)
      acc[mt][nt] = (floatx4){0.f, 0.f, 0.f, 0.f};

  float bv[8];
#pragma unroll
  for (int nt = 0; nt < 8; ++nt) bv[nt] = bias[nt * 16 + lrow];

#pragma unroll
  for (int ks = 0; ks < 4; ++ks) {
    int koff = ks * 32 + quad * 8;
    short8 a0 = *reinterpret_cast<const short8*>(&sA[(wave * 32 + lrow) * LDK + koff]);
    short8 a1 = *reinterpret_cast<const short8*>(&sA[(wave * 32 + 16 + lrow) * LDK + koff]);
#pragma unroll
    for (int nt = 0; nt < 8; ++nt) {
      short8 bb = *reinterpret_cast<const short8*>(&sW[(nt * 16 + lrow) * LDK + koff]);
      acc[0][nt] = __builtin_amdgcn_mfma_f32_16x16x32_bf16(a0, bb, acc[0][nt], 0, 0, 0);
      acc[1][nt] = __builtin_amdgcn_mfma_f32_16x16x32_bf16(a1, bb, acc[1][nt], 0, 0, 0);
    }
  }

#pragma unroll
  for (int mt = 0; mt < 2; ++mt) {
    int rbase = n0 + wave * 32 + mt * 16 + quad * 4;
#pragma unroll
    for (int reg = 0; reg < 4; ++reg) {
      int r = rbase + reg;
      if (r < N) {
        float* op = out + (size_t)r * D + lrow;
#pragma unroll
        for (int nt = 0; nt < 8; ++nt)
          op[nt * 16] = acc[mt][nt][reg] + bv[nt];
      }
    }
  }
}

// ---------------------------------------------------------------------------
// k_select_bucket_g: standalone fallback select (same structure as phase S),
// writes slots to global for the fp32 fallback path.
// ---------------------------------------------------------------------------
__global__ __launch_bounds__(256) void k_select_bucket_g(const uint2* __restrict__ binned,
                                                         const int* __restrict__ gcur,
                                                         int capb,
                                                         int* __restrict__ slots_g,
                                                         int N, int E) {
  __shared__ unsigned binE[NPB * SELPAD];
  __shared__ unsigned binC[NPB * SELPAD];
  __shared__ int scur[NPB];
  int b = blockIdx.x;
  int nbase = b << SHIFT;
  for (int i = threadIdx.x; i < NPB; i += 256) scur[i] = 0;
  __syncthreads();
  int cnt = gcur[b];
  cnt = min(max(cnt, 0), capb);
  for (int i = threadIdx.x; i < cnt; i += 256) {
    uint2 en = binned[(size_t)b * capb + i];
    int rl = (int)(en.x >> 24) & (NPB - 1);
    int k = atomicAdd(&scur[rl], 1);
    if (k < SCAP) {
      binE[rl * SELPAD + k] = en.x;
      binC[rl * SELPAD + k] = en.y;
    }
  }
  __syncthreads();
  int rl = threadIdx.x;
  if (rl < NPB && nbase + rl < N) {
    int c = min(scur[rl], SCAP);
    unsigned e10[KNB], c10[KNB];
#pragma unroll
    for (int k = 0; k < KNB; ++k) { e10[k] = 0xFFFFFFFFu; c10[k] = 0xFFFFFFFFu; }
    for (int k = 0; k < c; ++k) {
      unsigned ev = binE[rl * SELPAD + k] & 0xFFFFFFu;
      unsigned cv = binC[rl * SELPAD + k];
#pragma unroll
      for (int j = 0; j < KNB; ++j) {
        bool lt = ev < e10[j];
        unsigned te = lt ? e10[j] : ev;
        unsigned tc = lt ? c10[j] : cv;
        e10[j] = lt ? ev : e10[j];
        c10[j] = lt ? cv : c10[j];
        ev = te; cv = tc;
      }
    }
#pragma unroll
    for (int k = 0; k < KNB; ++k)
      slots_g[(size_t)(nbase + rl) * KNB + k] =
          (e10[k] < (unsigned)E) ? (int)c10[k] : -1;
  }
}

// ---------------------------------------------------------------------------
// fallback fp32 agg + GEMM (R2/R4-proven), cols-in-slots
// ---------------------------------------------------------------------------
__global__ __launch_bounds__(256) void k_agg(const float* __restrict__ x,
                                             const int* __restrict__ slots,
                                             float* __restrict__ agg,
                                             int N) {
  int wave = threadIdx.x >> 6;
  int lane = threadIdx.x & 63;
  int n = blockIdx.x * 4 + wave;
  if (n >= N) return;
  int c = -1;
  if (lane < KNB) c = slots[(size_t)n * KNB + lane];
  bool valid = (lane < KNB) && ((unsigned)c < (unsigned)N);
  unsigned long long m = __ballot(valid);
  int nsel = __popcll(m);
  float2 acc = make_float2(0.f, 0.f);
  if (nsel > 0) {
    unsigned long long mm = m;
    while (mm) {
      int j = (int)__builtin_ctzll(mm);
      mm &= mm - 1;
      int cj = __shfl(c, j);
      if ((unsigned)cj >= (unsigned)N) cj = 0;
      float2 v = reinterpret_cast<const float2*>(x + (size_t)cj * D)[lane];
      acc.x += v.x; acc.y += v.y;
    }
    float sc = 1.f / (float)nsel;
    acc.x *= sc; acc.y *= sc;
  } else {
    acc = reinterpret_cast<const float2*>(x + (size_t)n * D)[lane];
  }
  reinterpret_cast<float2*>(agg + (size_t)n * D)[lane] = acc;
}

#define BN 128
#define KC 32
#define LDP 132

__global__ __launch_bounds__(256) void k_gemm(const float* __restrict__ agg,
                                              const float* __restrict__ Wm,
                                              const float* __restrict__ bias,
                                              float* __restrict__ out, int N) {
  __shared__ float sA[KC][LDP];
  __shared__ float sW[KC][LDP];
  const int tid = threadIdx.x;
  const int tx = tid & 15;
  const int ty = tid >> 4;
  const int n0 = blockIdx.x * BN;

  float acc[8][8];
#pragma unroll
  for (int i = 0; i < 8; ++i)
#pragma unroll
    for (int j = 0; j < 8; ++j) acc[i][j] = 0.f;

  const int nl = tid >> 3;
  const int kq = tid & 7;

  for (int kc = 0; kc < D; kc += KC) {
#pragma unroll
    for (int i = 0; i < 4; ++i) {
      int rrow = nl + i * 32;
      int n = n0 + rrow;
      float4 av = make_float4(0.f, 0.f, 0.f, 0.f);
      if (n < N)
        av = reinterpret_cast<const float4*>(agg + (size_t)n * D + kc)[kq];
      int k = kq * 4;
      sA[k+0][rrow] = av.x; sA[k+1][rrow] = av.y;
      sA[k+2][rrow] = av.z; sA[k+3][rrow] = av.w;
      float4 wv = reinterpret_cast<const float4*>(Wm + (size_t)rrow * D + kc)[kq];
      sW[k+0][rrow] = wv.x; sW[k+1][rrow] = wv.y;
      sW[k+2][rrow] = wv.z; sW[k+3][rrow] = wv.w;
    }
    __syncthreads();
#pragma unroll
    for (int k = 0; k < KC; ++k) {
      float4 a0 = *reinterpret_cast<const float4*>(&sA[k][ty * 8]);
      float4 a1 = *reinterpret_cast<const float4*>(&sA[k][ty * 8 + 4]);
      float4 w0 = *reinterpret_cast<const float4*>(&sW[k][tx * 8]);
      float4 w1 = *reinterpret_cast<const float4*>(&sW[k][tx * 8 + 4]);
      float a[8] = {a0.x, a0.y, a0.z, a0.w, a1.x, a1.y, a1.z, a1.w};
      float w[8] = {w0.x, w0.y, w0.z, w0.w, w1.x, w1.y, w1.z, w1.w};
#pragma unroll
      for (int i = 0; i < 8; ++i)
#pragma unroll
        for (int j = 0; j < 8; ++j)
          acc[i][j] += a[i] * w[j];
    }
    __syncthreads();
  }

  float4 b0 = reinterpret_cast<const float4*>(bias)[tx * 2];
  float4 b1 = reinterpret_cast<const float4*>(bias)[tx * 2 + 1];
#pragma unroll
  for (int i = 0; i < 8; ++i) {
    int n = n0 + ty * 8 + i;
    if (n < N) {
      float4 v0 = make_float4(acc[i][0] + b0.x, acc[i][1] + b0.y,
                              acc[i][2] + b0.z, acc[i][3] + b0.w);
      float4 v1 = make_float4(acc[i][4] + b1.x, acc[i][5] + b1.y,
                              acc[i][6] + b1.z, acc[i][7] + b1.w);
      float4* op = reinterpret_cast<float4*>(out + (size_t)n * D + tx * 8);
      op[0] = v0;
      op[1] = v1;
    }
  }
}

// ---------------------------------------------------------------------------
extern "C" void kernel_launch(void* const* d_in, const int* in_sizes, int n_in,
                              void* d_out, int out_size, void* d_ws, size_t ws_size,
                              hipStream_t stream) {
  const float* x    = (const float*)d_in[0];
  const int*   ei   = (const int*)d_in[1];
  const float* Wm   = (const float*)d_in[2];
  const float* bias = (const float*)d_in[3];
  float* out = (float*)d_out;

  const int N = in_sizes[0] / D;
  const int E = in_sizes[1] / 2;
  const int NB = (N + NPB - 1) >> SHIFT;   // 782 for bench; must be <= MAXNB

  const int blocks_bin = (E + EPB - 1) / EPB;
  const int n8 = N * (D / 8);

  // ws layout (full path): gcur[NB] | binned[NB*CAPB uint2] | xh[N*64 u32]
  size_t off_binned = ((size_t)NB * 4 + 15) & ~(size_t)15;
  size_t off_xh = (off_binned + (size_t)NB * CAPB * 8 + 15) & ~(size_t)15;
  size_t need_full = off_xh + (size_t)N * D * 2;
  const bool have_full = (NB <= MAXNB) && (ws_size >= need_full);

  if (have_full) {
    int* gcur = (int*)d_ws;
    uint2* binned = (uint2*)((char*)d_ws + off_binned);
    unsigned* xh = (unsigned*)((char*)d_ws + off_xh);

    hipMemsetAsync(gcur, 0, (size_t)NB * 4, stream);
    k_scatter_xcast<<<blocks_bin + (n8 + T_BIN - 1) / T_BIN, T_BIN, 0, stream>>>(
        ei, ei + E, E, NB, CAPB, gcur, binned, blocks_bin, x, xh, n8);
    k_fused<<<NB, 256, 0, stream>>>(xh, x, binned, gcur, CAPB, Wm, bias, out, N, E);
  } else {
    // fallback (never on bench): binned in d_out (dead before k_agg writes),
    // gcur+slots in ws, fp32 agg + VALU GEMM.
    int* gcur = (int*)d_ws;
    size_t off_slots = ((size_t)NB * 4 + 15) & ~(size_t)15;
    int* slots = (int*)((char*)d_ws + off_slots);
    size_t out_bytes = (size_t)out_size * 4;
    int capb2 = (int)(out_bytes / ((size_t)NB * 8));
    if (capb2 > CAPB) capb2 = CAPB;
    if (capb2 < 1) capb2 = 1;
    uint2* binned = (uint2*)d_out;

    hipMemsetAsync(gcur, 0, (size_t)NB * 4, stream);
    k_scatter_xcast<<<blocks_bin, T_BIN, 0, stream>>>(
        ei, ei + E, E, NB, capb2, gcur, binned, blocks_bin, x, nullptr, 0);
    k_select_bucket_g<<<NB, 256, 0, stream>>>(binned, gcur, capb2, slots, N, E);
    k_agg<<<(N + 3) / 4, 256, 0, stream>>>(x, slots, out, N);
    k_gemm<<<(N + BN - 1) / BN, 256, 0, stream>>>(out, Wm, bias, out, N);
  }
}